// Round 11
// baseline (361.683 us; speedup 1.0000x reference)
//
#include <hip/hip_runtime.h>
#include <math.h>

#define IN_DIM 768
#define HID    1024
#define OUTD   18
#define BATCH  16
#define PERTSZ 64
#define IMH    512
#define IMW    512
#define LN_EPS 1e-5f

// ---------------------------------------------------------------------------
// Batched GEMM: y[b][j] = bias[j] + sum_k x[b][k] * Wm[k*N + j]  for ALL b.
// grid = N/32 blocks, block = 256 (32 cols x 8 row-groups of 2 rows).
// All 16 input rows staged in LDS; each weight element read ONCE total.
// ---------------------------------------------------------------------------
__global__ __launch_bounds__(256) void gemm_all(
    const float* __restrict__ x, const float* __restrict__ Wm,
    const float* __restrict__ bias, float* __restrict__ y, int K, int N)
{
    __shared__ float xs[BATCH * HID];        // up to 64 KB
    const int t = threadIdx.x;
    {   // cooperative float4 stage of all 16 rows (16*K floats, K%4==0)
        const float4* x4 = (const float4*)x;
        float4* xs4 = (float4*)xs;
        const int n4 = (BATCH * K) >> 2;
        for (int i = t; i < n4; i += 256) xs4[i] = x4[i];
    }
    __syncthreads();

    const int col = blockIdx.x * 32 + (t & 31);
    const int r0  = (t >> 5) * 2;            // rows r0, r0+1
    float acc0 = bias[col];
    float acc1 = acc0;
    const float* wc  = Wm + col;
    const float* xr0 = xs + r0 * K;
    const float* xr1 = xs + (r0 + 1) * K;
    #pragma unroll 8
    for (int k = 0; k < K; ++k) {
        const float w = wc[(size_t)k * N];
        acc0 += xr0[k] * w;
        acc1 += xr1[k] * w;
    }
    y[(size_t)r0 * N + col]       = acc0;
    y[(size_t)(r0 + 1) * N + col] = acc1;
}

// ---------------------------------------------------------------------------
// LayerNorm (N=1024) + ReLU. grid = B, block = 256 (4 elems/thread).
// ---------------------------------------------------------------------------
__global__ __launch_bounds__(256) void ln_relu_kernel(
    const float* __restrict__ y, const float* __restrict__ g,
    const float* __restrict__ be, float* __restrict__ x)
{
    __shared__ float red[4];
    const int b = blockIdx.x;
    const int t = threadIdx.x;
    const float* yr = y + b * HID;
    float v[4];
    #pragma unroll
    for (int i = 0; i < 4; ++i) v[i] = yr[t + i * 256];

    float s = v[0] + v[1] + v[2] + v[3];
    #pragma unroll
    for (int o = 32; o > 0; o >>= 1) s += __shfl_down(s, o, 64);
    const int wid = t >> 6, lane = t & 63;
    if (lane == 0) red[wid] = s;
    __syncthreads();
    const float m = (red[0] + red[1] + red[2] + red[3]) * (1.0f / HID);

    float sq = 0.f;
    #pragma unroll
    for (int i = 0; i < 4; ++i) { float d = v[i] - m; sq += d * d; }
    __syncthreads();   // before red[] reuse
    #pragma unroll
    for (int o = 32; o > 0; o >>= 1) sq += __shfl_down(sq, o, 64);
    if (lane == 0) red[wid] = sq;
    __syncthreads();
    const float var = (red[0] + red[1] + red[2] + red[3]) * (1.0f / HID);
    const float rstd = rsqrtf(var + LN_EPS);

    #pragma unroll
    for (int i = 0; i < 4; ++i) {
        const int j = t + i * 256;
        float o_ = (v[i] - m) * rstd * g[j] + be[j];
        x[b * HID + j] = fmaxf(o_, 0.0f);
    }
}

// ---------------------------------------------------------------------------
// Fused: layer-3 GEMM (K=1024 -> 18) + LN(18) + tanh + Gaussian patches +
// scattered add into out. grid = B, block = 256.
// pert = amp * exp(-0.5*(quad - min(quad)))  [normalization cancels exactly]
// ---------------------------------------------------------------------------
__global__ __launch_bounds__(256) void final_pert_patch(
    const float* __restrict__ x2, const float* __restrict__ W3,
    const float* __restrict__ b3, const float* __restrict__ g3,
    const float* __restrict__ be3, const int* __restrict__ loc,
    float* __restrict__ out)
{
    __shared__ float xs[HID];
    __shared__ float y3[OUTD];
    __shared__ float mv[2];
    __shared__ float red[4];
    const int b = blockIdx.x;
    const int t = threadIdx.x;
    for (int k = t; k < HID; k += 256) xs[k] = x2[b * HID + k];
    __syncthreads();

    // ---- layer-3 GEMM on wave 0: lane handles k = lane*16 .. lane*16+15
    if (t < 64) {
        float local[OUTD];
        #pragma unroll
        for (int j = 0; j < OUTD; ++j) local[j] = 0.f;
        const float* xk = xs + t * 16;
        const float* wk = W3 + t * 16 * OUTD;
        #pragma unroll 4
        for (int kk = 0; kk < 16; ++kk) {
            const float xv = xk[kk];
            #pragma unroll
            for (int j = 0; j < OUTD; ++j) local[j] += xv * wk[kk * OUTD + j];
        }
        #pragma unroll
        for (int j = 0; j < OUTD; ++j) {
            #pragma unroll
            for (int o = 32; o > 0; o >>= 1) local[j] += __shfl_xor(local[j], o, 64);
        }
        if (t < OUTD) y3[t] = local[t] + b3[t];
    }
    __syncthreads();

    // ---- LN over 18 (serial on t==0; trivial)
    if (t == 0) {
        float s = 0.f;
        for (int j = 0; j < OUTD; ++j) s += y3[j];
        const float m = s * (1.0f / OUTD);
        float sq = 0.f;
        for (int j = 0; j < OUTD; ++j) { float d = y3[j] - m; sq += d * d; }
        mv[0] = m;
        mv[1] = rsqrtf(sq * (1.0f / OUTD) + LN_EPS);
    }
    __syncthreads();
    if (t < OUTD) {
        const float tv = (y3[t] - mv[0]) * mv[1] * g3[t] + be3[t];
        y3[t] = tanhf(tv);
    }
    __syncthreads();

    // ---- per-channel Gaussian patch + scattered add
    const int r0 = loc[b * 2 + 0] - PERTSZ / 2;
    const int c0 = loc[b * 2 + 1] - PERTSZ / 2;
    const int wid = t >> 6, lane = t & 63;
    const float step = 64.0f / 63.0f;

    for (int ch = 0; ch < 3; ++ch) {
        const float* p = &y3[ch * 6];
        const float mean0 = p[0] * 32.0f;
        const float mean1 = p[1] * 32.0f;
        const float rs_ = (p[2] + 1.0f) * 15.5f + 1.0f;
        const float cs_ = (p[3] + 1.0f) * 15.5f + 1.0f;
        const float corr = p[4] * 0.98f;
        const float amp  = p[5];
        const float det = (rs_ * cs_) * (rs_ * cs_) * (1.0f - corr * corr);
        const float i00 = cs_ * cs_ / det;
        const float i11 = rs_ * rs_ / det;
        const float i01 = -(rs_ * cs_ * corr) / det;

        float q[16];
        float qmin = 1e30f;
        #pragma unroll
        for (int tt = 0; tt < 16; ++tt) {
            const int idx = t + tt * 256;
            const int i = idx >> 6, j = idx & 63;
            const float d0 = (-32.0f + i * step) - mean0;
            const float d1 = (-32.0f + j * step) - mean1;
            const float quad = i00 * d0 * d0 + 2.0f * i01 * d0 * d1 + i11 * d1 * d1;
            q[tt] = quad;
            qmin = fminf(qmin, quad);
        }
        #pragma unroll
        for (int o = 32; o > 0; o >>= 1) qmin = fminf(qmin, __shfl_xor(qmin, o, 64));
        if (lane == 0) red[wid] = qmin;
        __syncthreads();
        const float qm = fminf(fminf(red[0], red[1]), fminf(red[2], red[3]));

        float* base = out + ((size_t)(b * 3 + ch) * 2) * (IMH * IMW);
        #pragma unroll
        for (int tt = 0; tt < 16; ++tt) {
            const int idx = t + tt * 256;
            const int i = idx >> 6, j = idx & 63;
            const int r = r0 + i, c = c0 + j;
            if ((unsigned)r < (unsigned)IMH && (unsigned)c < (unsigned)IMW)
                base[(size_t)r * IMW + c] += amp * expf(-0.5f * (q[tt] - qm));
        }
        __syncthreads();   // red[] reused next channel
    }
}

// ---------------------------------------------------------------------------
// Full video copy (float4). grid-stride.
// ---------------------------------------------------------------------------
__global__ __launch_bounds__(256) void copy_kernel(
    const float4* __restrict__ src, float4* __restrict__ dst, int n4)
{
    int i = blockIdx.x * blockDim.x + threadIdx.x;
    const int stride = gridDim.x * blockDim.x;
    for (; i < n4; i += stride) dst[i] = src[i];
}

// ---------------------------------------------------------------------------
extern "C" void kernel_launch(void* const* d_in, const int* in_sizes, int n_in,
                              void* d_out, int out_size, void* d_ws, size_t ws_size,
                              hipStream_t stream)
{
    const float* video = (const float*)d_in[0];
    const float* enc   = (const float*)d_in[1];
    const int*   loc   = (const int*)  d_in[2];
    const float* W1 = (const float*)d_in[3];
    const float* b1 = (const float*)d_in[4];
    const float* g1 = (const float*)d_in[5];
    const float* be1= (const float*)d_in[6];
    const float* W2 = (const float*)d_in[7];
    const float* b2 = (const float*)d_in[8];
    const float* g2 = (const float*)d_in[9];
    const float* be2= (const float*)d_in[10];
    const float* W3 = (const float*)d_in[11];
    const float* b3 = (const float*)d_in[12];
    const float* g3 = (const float*)d_in[13];
    const float* be3= (const float*)d_in[14];
    float* out = (float*)d_out;

    float* ws = (float*)d_ws;
    float* y1 = ws;              // 16*1024
    float* x1 = ws + 16384;      // 16*1024
    float* y2 = ws + 32768;      // 16*1024
    float* x2 = ws + 49152;      // 16*1024

    // full-video copy first (longest pole, no deps)
    const int n4 = (BATCH * 3 * 2 * IMH * IMW) / 4;   // 6291456
    copy_kernel<<<2048, 256, 0, stream>>>((const float4*)video, (float4*)out, n4);

    // MLP chain (weights read exactly once per layer)
    gemm_all<<<HID / 32, 256, 0, stream>>>(enc, W1, b1, y1, IN_DIM, HID);
    ln_relu_kernel<<<BATCH, 256, 0, stream>>>(y1, g1, be1, x1);
    gemm_all<<<HID / 32, 256, 0, stream>>>(x1, W2, b2, y2, HID, HID);
    ln_relu_kernel<<<BATCH, 256, 0, stream>>>(y2, g2, be2, x2);

    // fused: final layer + LN + tanh + patch gen + scattered add
    final_pert_patch<<<BATCH, 256, 0, stream>>>(x2, W3, b3, g3, be3, loc, out);
}

// Round 12
// 249.409 us; speedup vs baseline: 1.4502x; 1.4502x over previous
//
#include <hip/hip_runtime.h>
#include <math.h>

#define IN_DIM 768
#define HID    1024
#define OUTD   18
#define BATCH  16
#define PERTSZ 64
#define IMH    512
#define IMW    512
#define LN_EPS 1e-5f

// Video layout: (16,3,2,512,512) fp32. Per (b,ch) pair: 2 frames x 262144
// floats = 131072 float4. Frame0 = first 65536 float4 of the pair ("slice"),
// frame1 = next 65536. 48 slices total per frame.
#define SLICE4  65536
#define PAIR4   131072

// ---------------------------------------------------------------------------
// Copy helper: copy-only blocks stream [sliceBase, sliceBase+nSlices) of the
// given frame (frameOff4 = 0 for f0, 65536 for f1) from src to dst.
// ---------------------------------------------------------------------------
__device__ __forceinline__ void copy_slices(const float4* __restrict__ src,
                                            float4* __restrict__ dst,
                                            int cb, int nCopy,
                                            int sliceBase, int nSlices,
                                            int frameOff4)
{
    const int bs = blockDim.x;
    const long total4 = (long)nSlices << 16;
    for (long v = (long)cb * bs + threadIdx.x; v < total4; v += (long)nCopy * bs) {
        const int s   = (int)(v >> 16);
        const int off = (int)(v & (SLICE4 - 1));
        const size_t i4 = (size_t)(sliceBase + s) * PAIR4 + frameOff4 + off;
        dst[i4] = src[i4];
    }
}

// ---------------------------------------------------------------------------
// GEMM stage (+ fused copy): y[b][col] = bias[col] + dot(x[b,:], W[:,col]).
// Compute blocks: 256 = 16 batches x 16 col-blocks of 64 cols. Block = 512
// threads = 64 cols x 8 K-slices; wave w == K-slice w, lanes = consecutive
// cols -> every W read is a 256B coalesced segment. LDS tree-reduce.
// ---------------------------------------------------------------------------
__global__ __launch_bounds__(512) void gemm_fused(
    const float* __restrict__ x, const float* __restrict__ W,
    const float* __restrict__ bias, float* __restrict__ y, int K, int N,
    const float4* __restrict__ csrc, float4* __restrict__ cdst,
    int sliceBase, int nSlices, int frameOff4, int nCompute, int nCopy)
{
    if ((int)blockIdx.x >= nCompute) {
        copy_slices(csrc, cdst, blockIdx.x - nCompute, nCopy,
                    sliceBase, nSlices, frameOff4);
        return;
    }
    __shared__ float xs[1024];
    __shared__ float red[512];
    const int b  = blockIdx.x >> 4;
    const int cb = blockIdx.x & 15;
    const int t  = threadIdx.x;

    for (int k = t; k < K; k += 512) xs[k] = x[b * K + k];
    __syncthreads();

    const int col    = cb * 64 + (t & 63);
    const int kq     = t >> 6;          // 0..7
    const int kchunk = K >> 3;          // 96 or 128 (both %8==0)
    const int k0     = kq * kchunk;
    float acc = 0.f;
    #pragma unroll 8
    for (int k = 0; k < kchunk; ++k)
        acc += xs[k0 + k] * W[(size_t)(k0 + k) * N + col];
    red[t] = acc;
    __syncthreads();

    if (t < 64) {
        float s = 0.f;
        #pragma unroll
        for (int q = 0; q < 8; ++q) s += red[q * 64 + t];
        y[b * N + cb * 64 + t] = s + bias[cb * 64 + t];
    }
}

// ---------------------------------------------------------------------------
// LayerNorm(1024)+ReLU stage (+ fused copy). Compute blocks: 16 (one/batch),
// 256 threads x 4 elems.
// ---------------------------------------------------------------------------
__global__ __launch_bounds__(256) void ln_fused(
    const float* __restrict__ y, const float* __restrict__ g,
    const float* __restrict__ be, float* __restrict__ x,
    const float4* __restrict__ csrc, float4* __restrict__ cdst,
    int sliceBase, int nSlices, int frameOff4, int nCompute, int nCopy)
{
    if ((int)blockIdx.x >= nCompute) {
        copy_slices(csrc, cdst, blockIdx.x - nCompute, nCopy,
                    sliceBase, nSlices, frameOff4);
        return;
    }
    __shared__ float red[4];
    const int b = blockIdx.x;
    const int t = threadIdx.x;
    const float* yr = y + b * HID;
    float v[4];
    #pragma unroll
    for (int i = 0; i < 4; ++i) v[i] = yr[t + i * 256];

    float s = v[0] + v[1] + v[2] + v[3];
    #pragma unroll
    for (int o = 32; o > 0; o >>= 1) s += __shfl_down(s, o, 64);
    const int wid = t >> 6, lane = t & 63;
    if (lane == 0) red[wid] = s;
    __syncthreads();
    const float m = (red[0] + red[1] + red[2] + red[3]) * (1.0f / HID);

    float sq = 0.f;
    #pragma unroll
    for (int i = 0; i < 4; ++i) { float d = v[i] - m; sq += d * d; }
    __syncthreads();
    #pragma unroll
    for (int o = 32; o > 0; o >>= 1) sq += __shfl_down(sq, o, 64);
    if (lane == 0) red[wid] = sq;
    __syncthreads();
    const float var = (red[0] + red[1] + red[2] + red[3]) * (1.0f / HID);
    const float rstd = rsqrtf(var + LN_EPS);

    #pragma unroll
    for (int i = 0; i < 4; ++i) {
        const int j = t + i * 256;
        float o_ = (v[i] - m) * rstd * g[j] + be[j];
        x[b * HID + j] = fmaxf(o_, 0.0f);
    }
}

// ---------------------------------------------------------------------------
// Final stage (+ fused copy of ALL frame-1 slices — frame1 is untouched by
// the patch, so no ordering hazard): layer-3 GEMM (K=1024 -> 18) + LN(18) +
// tanh + Gaussian patches + scattered add into out (frame 0).
// pert = amp * exp(-0.5*(quad - min(quad)))   [normalization cancels exactly]
// ---------------------------------------------------------------------------
__global__ __launch_bounds__(256) void final_fused(
    const float* __restrict__ x2, const float* __restrict__ W3,
    const float* __restrict__ b3, const float* __restrict__ g3,
    const float* __restrict__ be3, const int* __restrict__ loc,
    float* __restrict__ out,
    const float4* __restrict__ csrc, float4* __restrict__ cdst,
    int sliceBase, int nSlices, int frameOff4, int nCompute, int nCopy)
{
    if ((int)blockIdx.x >= nCompute) {
        copy_slices(csrc, cdst, blockIdx.x - nCompute, nCopy,
                    sliceBase, nSlices, frameOff4);
        return;
    }
    __shared__ float xs[HID];
    __shared__ float y3[OUTD];
    __shared__ float mv[2];
    __shared__ float red[4];
    const int b = blockIdx.x;
    const int t = threadIdx.x;
    for (int k = t; k < HID; k += 256) xs[k] = x2[b * HID + k];
    __syncthreads();

    // layer-3 GEMM on wave 0: lane handles k = lane*16 .. lane*16+15
    if (t < 64) {
        float local[OUTD];
        #pragma unroll
        for (int j = 0; j < OUTD; ++j) local[j] = 0.f;
        const float* xk = xs + t * 16;
        const float* wk = W3 + t * 16 * OUTD;
        #pragma unroll 4
        for (int kk = 0; kk < 16; ++kk) {
            const float xv = xk[kk];
            #pragma unroll
            for (int j = 0; j < OUTD; ++j) local[j] += xv * wk[kk * OUTD + j];
        }
        #pragma unroll
        for (int j = 0; j < OUTD; ++j) {
            #pragma unroll
            for (int o = 32; o > 0; o >>= 1) local[j] += __shfl_xor(local[j], o, 64);
        }
        if (t < OUTD) y3[t] = local[t] + b3[t];
    }
    __syncthreads();

    if (t == 0) {
        float s = 0.f;
        for (int j = 0; j < OUTD; ++j) s += y3[j];
        const float m = s * (1.0f / OUTD);
        float sq = 0.f;
        for (int j = 0; j < OUTD; ++j) { float d = y3[j] - m; sq += d * d; }
        mv[0] = m;
        mv[1] = rsqrtf(sq * (1.0f / OUTD) + LN_EPS);
    }
    __syncthreads();
    if (t < OUTD) {
        const float tv = (y3[t] - mv[0]) * mv[1] * g3[t] + be3[t];
        y3[t] = tanhf(tv);
    }
    __syncthreads();

    const int r0 = loc[b * 2 + 0] - PERTSZ / 2;
    const int c0 = loc[b * 2 + 1] - PERTSZ / 2;
    const int wid = t >> 6, lane = t & 63;
    const float step = 64.0f / 63.0f;

    for (int ch = 0; ch < 3; ++ch) {
        const float* p = &y3[ch * 6];
        const float mean0 = p[0] * 32.0f;
        const float mean1 = p[1] * 32.0f;
        const float rs_ = (p[2] + 1.0f) * 15.5f + 1.0f;
        const float cs_ = (p[3] + 1.0f) * 15.5f + 1.0f;
        const float corr = p[4] * 0.98f;
        const float amp  = p[5];
        const float det = (rs_ * cs_) * (rs_ * cs_) * (1.0f - corr * corr);
        const float i00 = cs_ * cs_ / det;
        const float i11 = rs_ * rs_ / det;
        const float i01 = -(rs_ * cs_ * corr) / det;

        float q[16];
        float qmin = 1e30f;
        #pragma unroll
        for (int tt = 0; tt < 16; ++tt) {
            const int idx = t + tt * 256;
            const int i = idx >> 6, j = idx & 63;
            const float d0 = (-32.0f + i * step) - mean0;
            const float d1 = (-32.0f + j * step) - mean1;
            const float quad = i00 * d0 * d0 + 2.0f * i01 * d0 * d1 + i11 * d1 * d1;
            q[tt] = quad;
            qmin = fminf(qmin, quad);
        }
        #pragma unroll
        for (int o = 32; o > 0; o >>= 1) qmin = fminf(qmin, __shfl_xor(qmin, o, 64));
        if (lane == 0) red[wid] = qmin;
        __syncthreads();
        const float qm = fminf(fminf(red[0], red[1]), fminf(red[2], red[3]));

        float* base = out + ((size_t)(b * 3 + ch) * 2) * (IMH * IMW);
        #pragma unroll
        for (int tt = 0; tt < 16; ++tt) {
            const int idx = t + tt * 256;
            const int i = idx >> 6, j = idx & 63;
            const int r = r0 + i, c = c0 + j;
            if ((unsigned)r < (unsigned)IMH && (unsigned)c < (unsigned)IMW)
                base[(size_t)r * IMW + c] += amp * expf(-0.5f * (q[tt] - qm));
        }
        __syncthreads();
    }
}

// ---------------------------------------------------------------------------
extern "C" void kernel_launch(void* const* d_in, const int* in_sizes, int n_in,
                              void* d_out, int out_size, void* d_ws, size_t ws_size,
                              hipStream_t stream)
{
    const float* video = (const float*)d_in[0];
    const float* enc   = (const float*)d_in[1];
    const int*   loc   = (const int*)  d_in[2];
    const float* W1 = (const float*)d_in[3];
    const float* b1 = (const float*)d_in[4];
    const float* g1 = (const float*)d_in[5];
    const float* be1= (const float*)d_in[6];
    const float* W2 = (const float*)d_in[7];
    const float* b2 = (const float*)d_in[8];
    const float* g2 = (const float*)d_in[9];
    const float* be2= (const float*)d_in[10];
    const float* W3 = (const float*)d_in[11];
    const float* b3 = (const float*)d_in[12];
    const float* g3 = (const float*)d_in[13];
    const float* be3= (const float*)d_in[14];
    float* out = (float*)d_out;

    float* ws = (float*)d_ws;
    float* y1 = ws;              // 16*1024
    float* x1 = ws + 16384;      // 16*1024
    float* y2 = ws + 32768;      // 16*1024
    float* x2 = ws + 49152;      // 16*1024

    const float4* v4 = (const float4*)video;
    float4*       o4 = (float4*)out;

    // Frame-0 (48 slices) copied across stages A-D; frame-1 (48 slices) in E,
    // concurrent with patch compute (patch touches only frame 0).
    const int AC = 768, BC = 1024, CC = 768, DC = 1024, EC = 2048;

    gemm_fused<<<256 + AC, 512, 0, stream>>>(enc, W1, b1, y1, IN_DIM, HID,
                                             v4, o4,  0, 12, 0, 256, AC);
    ln_fused  <<< 16 + BC, 256, 0, stream>>>(y1, g1, be1, x1,
                                             v4, o4, 12, 12, 0,  16, BC);
    gemm_fused<<<256 + CC, 512, 0, stream>>>(x1, W2, b2, y2, HID, HID,
                                             v4, o4, 24, 12, 0, 256, CC);
    ln_fused  <<< 16 + DC, 256, 0, stream>>>(y2, g2, be2, x2,
                                             v4, o4, 36, 12, 0,  16, DC);
    final_fused<<<16 + EC, 256, 0, stream>>>(x2, W3, b3, g3, be3, loc, out,
                                             v4, o4,  0, 48, SLICE4, 16, EC);
}